// Round 14
// baseline (124.896 us; speedup 1.0000x reference)
//
#include <hip/hip_runtime.h>
#include <hip/hip_bf16.h>

#define NN 100000
#define NE 1600000
#define IN_F 128
#define OUT_F 64
#define NBINS 782     // ceil(NN / 128)
#define BIN_SHIFT 7   // 128 nodes per bin
#define GEMM_WGS 1563 // ceil(NN / 64)
#define P1_WGS 391    // ceil(NE / 4096)
#define NREP2 8       // sub-slab replicas per bin
#define SUBCAP 384    // per (bin,rep); mean 256, sigma 16 -> 8-sigma slack
#define BINCAP (NREP2 * SUBCAP)  // 3072 records max per bin

typedef __attribute__((ext_vector_type(8))) short bf16x8;
typedef __attribute__((ext_vector_type(4))) float f32x4;

__device__ __forceinline__ short f2bf(float f) {
  unsigned u = __float_as_uint(f);
  unsigned r = (u + 0x7fffu + ((u >> 16) & 1u)) >> 16;  // RNE
  return (short)r;
}
__device__ __forceinline__ float bf2f(ushort u) {
  return __uint_as_float(((unsigned)u) << 16);
}

// ---------------- Kernel 0: wvt[j][k] = bf16(Wv[k][j]); block 0 zeroes bincur
__global__ __launch_bounds__(256) void prep_w(
    const float* __restrict__ Wv, short* __restrict__ wvt,
    int* __restrict__ bincur) {
  if (blockIdx.x == 0)
    for (int i = threadIdx.x; i < NREP2 * NBINS; i += 256) bincur[i] = 0;
  const int i = blockIdx.x * 256 + threadIdx.x;
  if (i >= IN_F * OUT_F) return;
  const int j = i >> 7, k = i & 127;
  wvt[i] = f2bf(Wv[k * OUT_F + j]);
}

// ---------------- Fused dispatch: blocks [0,GEMM_WGS) = node transform;
// blocks [GEMM_WGS, +P1_WGS) = edge binning into self-reserved sub-slabs.
__global__ __launch_bounds__(256) void fused_tp(
    const float* __restrict__ x, const short* __restrict__ wvt,
    const float* __restrict__ bv, const float* __restrict__ wq,
    const float* __restrict__ bq, const float* __restrict__ wk,
    const float* __restrict__ bk,
    ushort* __restrict__ xvb, float* __restrict__ el, float* __restrict__ er,
    const int* __restrict__ src, const int* __restrict__ dst,
    int* __restrict__ bincur, unsigned* __restrict__ slab) {
  if (blockIdx.x >= GEMM_WGS) {
    // ----- bin_pass1 body -----
    __shared__ int hist[NBINS];
    __shared__ int base_[NBINS];
    const int pb = blockIdx.x - GEMM_WGS;
    const int t = threadIdx.x;
    const int rep = pb & (NREP2 - 1);
    for (int i = t; i < NBINS; i += 256) hist[i] = 0;
    __syncthreads();
    const int e0 = pb * 4096;
    int sv[16], dv[16];
#pragma unroll
    for (int r = 0; r < 16; ++r) {
      const int i = e0 + r * 256 + t;
      if (i < NE) {
        sv[r] = src[i];
        dv[r] = dst[i];
        atomicAdd(&hist[dv[r] >> BIN_SHIFT], 1);
      } else {
        sv[r] = -1;
        dv[r] = 0;
      }
    }
    __syncthreads();
    for (int b = t; b < NBINS; b += 256) {
      base_[b] = (hist[b] > 0) ? atomicAdd(&bincur[rep * NBINS + b], hist[b]) : 0;
      hist[b] = 0;  // reuse as local cursor
    }
    __syncthreads();
#pragma unroll
    for (int r = 0; r < 16; ++r) {
      if (sv[r] >= 0) {
        const int s = sv[r], d = dv[r];
        const int b = d >> BIN_SHIFT;
        const unsigned dl = (unsigned)(d & 127);
        const int pos = base_[b] + atomicAdd(&hist[b], 1);
        slab[(size_t)(b * NREP2 + rep) * SUBCAP + pos] = (dl << 17) | (unsigned)s;
      }
    }
    return;
  }

  // ----- node_transform body -----
  const int wave = threadIdx.x >> 6, lane = threadIdx.x & 63;
  const int node0 = blockIdx.x * 64 + wave * 16;
  const int j15 = lane & 15, g = lane >> 4;
  const int kb = g * 8;

  int row = node0 + j15;
  if (row >= NN) row = NN - 1;
  const float* xr = x + (size_t)row * IN_F;
  bf16x8 a[4];
#pragma unroll
  for (int kt = 0; kt < 4; ++kt) {
    const float4 f0 = *(const float4*)(xr + kt * 32 + kb);
    const float4 f1 = *(const float4*)(xr + kt * 32 + kb + 4);
    bf16x8 t;
    t[0] = f2bf(f0.x); t[1] = f2bf(f0.y); t[2] = f2bf(f0.z); t[3] = f2bf(f0.w);
    t[4] = f2bf(f1.x); t[5] = f2bf(f1.y); t[6] = f2bf(f1.z); t[7] = f2bf(f1.w);
    a[kt] = t;
  }

  bf16x8 b[16];
#pragma unroll
  for (int nt = 0; nt < 4; ++nt)
#pragma unroll
    for (int kt = 0; kt < 4; ++kt)
      b[nt * 4 + kt] = *(const bf16x8*)(wvt + (size_t)(nt * 16 + j15) * IN_F + kt * 32 + kb);

  f32x4 acc[4];
#pragma unroll
  for (int nt = 0; nt < 4; ++nt) acc[nt] = (f32x4){0.f, 0.f, 0.f, 0.f};
#pragma unroll
  for (int nt = 0; nt < 4; ++nt)
#pragma unroll
    for (int kt = 0; kt < 4; ++kt)
      acc[nt] = __builtin_amdgcn_mfma_f32_16x16x32_bf16(a[kt], b[nt * 4 + kt], acc[nt], 0, 0, 0);

  float bvl[4], wql[4], wkl[4];
#pragma unroll
  for (int nt = 0; nt < 4; ++nt) {
    bvl[nt] = bv[nt * 16 + j15];
    wql[nt] = wq[nt * 16 + j15];
    wkl[nt] = wk[nt * 16 + j15];
  }
  const float bq0 = bq[0], bk0 = bk[0];

#pragma unroll
  for (int r = 0; r < 4; ++r) {
    const int node = node0 + g * 4 + r;
    float pq = 0.f, pk = 0.f;
#pragma unroll
    for (int nt = 0; nt < 4; ++nt) {
      const float v = acc[nt][r] + bvl[nt];
      if (node < NN) xvb[(size_t)node * OUT_F + nt * 16 + j15] = (ushort)f2bf(v);
      pq += v * wql[nt];
      pk += v * wkl[nt];
    }
#pragma unroll
    for (int o = 1; o < 16; o <<= 1) {
      pq += __shfl_xor(pq, o);
      pk += __shfl_xor(pk, o);
    }
    if (j15 == 0 && node < NN) {
      el[node] = pq + bq0;
      er[node] = pk + bk0;
    }
  }
}

// ---------------- Merged Phase 2+3: one wg per 128-node bin.
// Slab -> LDS per-node lists (hist+scan+cursor scatter, e computed inline),
// then per-node softmax + weighted xvb gather straight from LDS. No CSR.
__global__ __launch_bounds__(256) void bin_aggregate(
    const unsigned* __restrict__ slab, const int* __restrict__ bincur,
    const float* __restrict__ el, const float* __restrict__ er,
    const ushort* __restrict__ xvb, float* __restrict__ out) {
  __shared__ uint2 recs[BINCAP];   // 24 KB: (src, e_bits) per edge
  __shared__ int sbase[129];
  __shared__ int cur[128];
  __shared__ float er_l[128];
  __shared__ int sp[256];
  const int b = blockIdx.x, t = threadIdx.x;
  const int n0 = b << BIN_SHIFT;

  if (t < 128) {
    cur[t] = 0;
    const int n = n0 + t;
    er_l[t] = (n < NN) ? er[n] : 0.f;
  }
  __syncthreads();

  int repcnt[NREP2];
#pragma unroll
  for (int r = 0; r < NREP2; ++r) repcnt[r] = bincur[r * NBINS + b];

  // pass A: per-node histogram over the bin's 8 sub-slabs
#pragma unroll
  for (int rep = 0; rep < NREP2; ++rep) {
    const unsigned* sl = slab + (size_t)(b * NREP2 + rep) * SUBCAP;
    for (int i = t; i < repcnt[rep]; i += 256)
      atomicAdd(&cur[sl[i] >> 17], 1);
  }
  __syncthreads();

  // scan 128 counts -> sbase (cursors reset to base)
  const int cme = (t < 128) ? cur[t] : 0;
  sp[t] = cme;
  __syncthreads();
  for (int o = 1; o < 128; o <<= 1) {
    const int u = (t >= o && t < 128) ? sp[t - o] : 0;
    __syncthreads();
    if (t < 128) sp[t] += u;
    __syncthreads();
  }
  if (t < 128) {
    sbase[t] = sp[t] - cme;
    cur[t] = sp[t] - cme;
  }
  if (t == 127) sbase[128] = sp[127];
  __syncthreads();

  // pass B: compute e, cursor-scatter (src, e) into LDS recs (slab L2-hot)
#pragma unroll
  for (int rep = 0; rep < NREP2; ++rep) {
    const unsigned* sl = slab + (size_t)(b * NREP2 + rep) * SUBCAP;
    for (int i = t; i < repcnt[rep]; i += 256) {
      const unsigned w = sl[i];
      const int dl = (int)(w >> 17);
      const int s = (int)(w & 0x1FFFFu);
      float e = el[s] + er_l[dl];
      e = e > 0.f ? e : 0.2f * e;
      const int pos = atomicAdd(&cur[dl], 1);
      recs[pos] = (uint2){(unsigned)s, __float_as_uint(e)};
    }
  }
  __syncthreads();

  // per-node softmax + gather: wave w handles nodes w, w+4, ...
  const int wave = t >> 6, lane = t & 63;
  for (int n = wave; n < 128; n += 4) {
    const int node = n0 + n;
    if (node >= NN) break;  // wave-uniform
    const int base = sbase[n];
    const int deg = sbase[n + 1] - base;

    if (deg <= 64) {
      const bool valid = lane < deg;
      uint2 w = valid ? recs[base + lane] : (uint2){0u, 0u};
      int s = (int)w.x;
      float p = valid ? __expf(__uint_as_float(w.y)) : 0.f;
      float tt = p;
#pragma unroll
      for (int o = 32; o; o >>= 1) tt += __shfl_xor(tt, o);
      p *= (deg > 0) ? (1.0f / tt) : 0.f;

      const int fgrp = lane & 7, egrp = lane >> 3;
      float4 aLo = {0.f, 0.f, 0.f, 0.f};
      float4 aHi = {0.f, 0.f, 0.f, 0.f};
      const int nr = (deg + 7) >> 3;
#pragma unroll 4
      for (int r = 0; r < nr; ++r) {
        const int k = (r << 3) + egrp;
        const int sk = __shfl(s, k);
        const float pk = __shfl(p, k);
        if (k < deg) {
          const uint4 v = *(const uint4*)(xvb + (size_t)sk * OUT_F + (fgrp << 3));
          aLo.x += pk * __uint_as_float(v.x << 16);
          aLo.y += pk * __uint_as_float(v.x & 0xffff0000u);
          aLo.z += pk * __uint_as_float(v.y << 16);
          aLo.w += pk * __uint_as_float(v.y & 0xffff0000u);
          aHi.x += pk * __uint_as_float(v.z << 16);
          aHi.y += pk * __uint_as_float(v.z & 0xffff0000u);
          aHi.z += pk * __uint_as_float(v.w << 16);
          aHi.w += pk * __uint_as_float(v.w & 0xffff0000u);
        }
      }
#pragma unroll
      for (int o = 8; o <= 32; o <<= 1) {
        aLo.x += __shfl_xor(aLo.x, o);
        aLo.y += __shfl_xor(aLo.y, o);
        aLo.z += __shfl_xor(aLo.z, o);
        aLo.w += __shfl_xor(aLo.w, o);
        aHi.x += __shfl_xor(aHi.x, o);
        aHi.y += __shfl_xor(aHi.y, o);
        aHi.z += __shfl_xor(aHi.z, o);
        aHi.w += __shfl_xor(aHi.w, o);
      }
      if (egrp == 0) {
        float* op = out + (size_t)node * OUT_F + (fgrp << 3);
        *(float4*)op = aLo;
        *(float4*)(op + 4) = aHi;
      }
    } else {
      // fallback (deg>64, astronomically rare): stable 3-pass from LDS
      float m = -3.0e38f;
      for (int k = lane; k < deg; k += 64) m = fmaxf(m, __uint_as_float(recs[base + k].y));
#pragma unroll
      for (int o = 32; o; o >>= 1) m = fmaxf(m, __shfl_xor(m, o));
      float ssum = 0.f;
      for (int k = lane; k < deg; k += 64) ssum += __expf(__uint_as_float(recs[base + k].y) - m);
#pragma unroll
      for (int o = 32; o; o >>= 1) ssum += __shfl_xor(ssum, o);
      const float inv = 1.0f / ssum;
      float acc = 0.f;
      for (int k = 0; k < deg; ++k) {
        const uint2 w = recs[base + k];
        const float pk = __expf(__uint_as_float(w.y) - m) * inv;
        acc += pk * bf2f(xvb[(size_t)w.x * OUT_F + lane]);
      }
      out[(size_t)node * OUT_F + lane] = acc;
    }
  }
}

extern "C" void kernel_launch(void* const* d_in, const int* in_sizes, int n_in,
                              void* d_out, int out_size, void* d_ws, size_t ws_size,
                              hipStream_t stream) {
  const float* x  = (const float*)d_in[0];
  const float* Wv = (const float*)d_in[1];
  const float* bv = (const float*)d_in[2];
  const float* wq = (const float*)d_in[3];
  const float* bq = (const float*)d_in[4];
  const float* wk = (const float*)d_in[5];
  const float* bk = (const float*)d_in[6];
  const int* src  = (const int*)d_in[7];
  const int* dst  = (const int*)d_in[8];
  float* out = (float*)d_out;

  // workspace layout (4-byte words), ~23 MB total:
  // xvb[NN*64 ushort] el[NN] er[NN] slab[NBINS*NREP2*SUBCAP uint]
  // wvt[8192 short] bincur[NREP2*NBINS]
  ushort* xvb = (ushort*)d_ws;
  float* el = (float*)(xvb + (size_t)NN * OUT_F);
  float* er = el + NN;
  unsigned* slab = (unsigned*)(er + NN);
  short* wvt = (short*)(slab + (size_t)NBINS * NREP2 * SUBCAP);
  int* bincur = (int*)(wvt + IN_F * OUT_F);

  prep_w<<<(IN_F * OUT_F + 255) / 256, 256, 0, stream>>>(Wv, wvt, bincur);
  fused_tp<<<GEMM_WGS + P1_WGS, 256, 0, stream>>>(x, wvt, bv, wq, bq, wk, bk,
                                                  xvb, el, er, src, dst, bincur, slab);
  bin_aggregate<<<NBINS, 256, 0, stream>>>(slab, bincur, el, er, xvb, out);
}

// Round 15
// 112.220 us; speedup vs baseline: 1.1130x; 1.1130x over previous
//
#include <hip/hip_runtime.h>
#include <hip/hip_bf16.h>

#define NN 100000
#define NE 1600000
#define IN_F 128
#define OUT_F 64
#define NBINS 782     // ceil(NN / 128)
#define BIN_SHIFT 7   // 128 nodes per bin
#define GEMM_WGS 391  // ceil(NN / 256): 256 nodes per block, 64 per wave
#define P1_WGS 391    // ceil(NE / 4096)
#define NREP2 8       // sub-slab replicas per bin
#define SUBCAP 384    // per (bin,rep); mean 256, sigma 16 -> 8-sigma slack

typedef __attribute__((ext_vector_type(8))) short bf16x8;
typedef __attribute__((ext_vector_type(4))) float f32x4;

__device__ __forceinline__ short f2bf(float f) {
  unsigned u = __float_as_uint(f);
  unsigned r = (u + 0x7fffu + ((u >> 16) & 1u)) >> 16;  // RNE
  return (short)r;
}
__device__ __forceinline__ float bf2f(ushort u) {
  return __uint_as_float(((unsigned)u) << 16);
}

// ---------------- Kernel 0: wvt[j][k] = bf16(Wv[k][j]); block 0 zeroes bincur
__global__ __launch_bounds__(256) void prep_w(
    const float* __restrict__ Wv, short* __restrict__ wvt,
    int* __restrict__ bincur) {
  if (blockIdx.x == 0)
    for (int i = threadIdx.x; i < NREP2 * NBINS; i += 256) bincur[i] = 0;
  const int i = blockIdx.x * 256 + threadIdx.x;
  if (i >= IN_F * OUT_F) return;
  const int j = i >> 7, k = i & 127;
  wvt[i] = f2bf(Wv[k * OUT_F + j]);
}

// ---------------- Fused dispatch: blocks [0,GEMM_WGS) = node transform
// (64 nodes/wave: b-frags loaded once, 4 tiles of 16 nodes);
// blocks [GEMM_WGS, +P1_WGS) = edge binning into self-reserved sub-slabs.
__global__ __launch_bounds__(256) void fused_tp(
    const float* __restrict__ x, const short* __restrict__ wvt,
    const float* __restrict__ bv, const float* __restrict__ wq,
    const float* __restrict__ bq, const float* __restrict__ wk,
    const float* __restrict__ bk,
    ushort* __restrict__ xvb, float* __restrict__ el, float* __restrict__ er,
    const int* __restrict__ src, const int* __restrict__ dst,
    int* __restrict__ bincur, unsigned* __restrict__ slab) {
  if (blockIdx.x >= GEMM_WGS) {
    // ----- bin_pass1 body -----
    __shared__ int hist[NBINS];
    __shared__ int base_[NBINS];
    const int pb = blockIdx.x - GEMM_WGS;
    const int t = threadIdx.x;
    const int rep = pb & (NREP2 - 1);
    for (int i = t; i < NBINS; i += 256) hist[i] = 0;
    __syncthreads();
    const int e0 = pb * 4096;
    int sv[16], dv[16];
#pragma unroll
    for (int r = 0; r < 16; ++r) {
      const int i = e0 + r * 256 + t;
      if (i < NE) {
        sv[r] = src[i];
        dv[r] = dst[i];
        atomicAdd(&hist[dv[r] >> BIN_SHIFT], 1);
      } else {
        sv[r] = -1;
        dv[r] = 0;
      }
    }
    __syncthreads();
    for (int b = t; b < NBINS; b += 256) {
      base_[b] = (hist[b] > 0) ? atomicAdd(&bincur[rep * NBINS + b], hist[b]) : 0;
      hist[b] = 0;  // reuse as local cursor
    }
    __syncthreads();
#pragma unroll
    for (int r = 0; r < 16; ++r) {
      if (sv[r] >= 0) {
        const int s = sv[r], d = dv[r];
        const int b = d >> BIN_SHIFT;
        const unsigned dl = (unsigned)(d & 127);
        const int pos = base_[b] + atomicAdd(&hist[b], 1);
        slab[(size_t)(b * NREP2 + rep) * SUBCAP + pos] = (dl << 17) | (unsigned)s;
      }
    }
    return;
  }

  // ----- node_transform body: 64 nodes per wave, B amortized over 4 tiles -----
  const int wave = threadIdx.x >> 6, lane = threadIdx.x & 63;
  const int wnode0 = blockIdx.x * 256 + wave * 64;
  const int j15 = lane & 15, g = lane >> 4;
  const int kb = g * 8;

  // B fragments: loaded ONCE per wave (16 x 16B, L2-hot)
  bf16x8 b[16];
#pragma unroll
  for (int nt = 0; nt < 4; ++nt)
#pragma unroll
    for (int kt = 0; kt < 4; ++kt)
      b[nt * 4 + kt] = *(const bf16x8*)(wvt + (size_t)(nt * 16 + j15) * IN_F + kt * 32 + kb);

  float bvl[4], wql[4], wkl[4];
#pragma unroll
  for (int nt = 0; nt < 4; ++nt) {
    bvl[nt] = bv[nt * 16 + j15];
    wql[nt] = wq[nt * 16 + j15];
    wkl[nt] = wk[nt * 16 + j15];
  }
  const float bq0 = bq[0], bk0 = bk[0];

#pragma unroll
  for (int tile = 0; tile < 4; ++tile) {
    const int node0 = wnode0 + tile * 16;
    int row = node0 + j15;
    if (row >= NN) row = NN - 1;
    const float* xr = x + (size_t)row * IN_F;
    bf16x8 a[4];
#pragma unroll
    for (int kt = 0; kt < 4; ++kt) {
      const float4 f0 = *(const float4*)(xr + kt * 32 + kb);
      const float4 f1 = *(const float4*)(xr + kt * 32 + kb + 4);
      bf16x8 t;
      t[0] = f2bf(f0.x); t[1] = f2bf(f0.y); t[2] = f2bf(f0.z); t[3] = f2bf(f0.w);
      t[4] = f2bf(f1.x); t[5] = f2bf(f1.y); t[6] = f2bf(f1.z); t[7] = f2bf(f1.w);
      a[kt] = t;
    }

    f32x4 acc[4];
#pragma unroll
    for (int nt = 0; nt < 4; ++nt) acc[nt] = (f32x4){0.f, 0.f, 0.f, 0.f};
#pragma unroll
    for (int nt = 0; nt < 4; ++nt)
#pragma unroll
      for (int kt = 0; kt < 4; ++kt)
        acc[nt] = __builtin_amdgcn_mfma_f32_16x16x32_bf16(a[kt], b[nt * 4 + kt], acc[nt], 0, 0, 0);

#pragma unroll
    for (int r = 0; r < 4; ++r) {
      const int node = node0 + g * 4 + r;
      float pq = 0.f, pk = 0.f;
#pragma unroll
      for (int nt = 0; nt < 4; ++nt) {
        const float v = acc[nt][r] + bvl[nt];
        if (node < NN) xvb[(size_t)node * OUT_F + nt * 16 + j15] = (ushort)f2bf(v);
        pq += v * wql[nt];
        pk += v * wkl[nt];
      }
#pragma unroll
      for (int o = 1; o < 16; o <<= 1) {
        pq += __shfl_xor(pq, o);
        pk += __shfl_xor(pk, o);
      }
      if (j15 == 0 && node < NN) {
        el[node] = pq + bq0;
        er[node] = pk + bk0;
      }
    }
  }
}

// ---------------- Phase 2: one wg per 128-node bin. Redundant bin-level scan
// (L2-hot bincur), LDS per-node hist+scan -> off[], compute e, write csr.
__global__ __launch_bounds__(256) void bin_scatter(
    const unsigned* __restrict__ slab, const int* __restrict__ bincur,
    const float* __restrict__ el, const float* __restrict__ er,
    int* __restrict__ off, uint2* __restrict__ csr) {
  __shared__ int sp[256];
  __shared__ int cnt[128];     // counts, then cursors
  __shared__ float er_l[128];
  __shared__ int s_csr0;
  const int b = blockIdx.x, t = threadIdx.x;
  const int n0 = b << BIN_SHIFT;

  // redundant bin-level exclusive scan: thread t covers bins 4t..4t+3
  int v = 0;
#pragma unroll
  for (int j = 0; j < 4; ++j) {
    const int bb = 4 * t + j;
    if (bb < NBINS) {
#pragma unroll
      for (int r = 0; r < NREP2; ++r) v += bincur[r * NBINS + bb];
    }
  }
  sp[t] = v;
  __syncthreads();
  for (int o = 1; o < 256; o <<= 1) {
    const int u = (t >= o) ? sp[t - o] : 0;
    __syncthreads();
    sp[t] += u;
    __syncthreads();
  }
  if (t == 0) {
    const int q = b >> 2, rr = b & 3;
    int c = (q > 0) ? sp[q - 1] : 0;
    for (int j = 0; j < rr; ++j)
      for (int r = 0; r < NREP2; ++r) c += bincur[r * NBINS + (4 * q + j)];
    s_csr0 = c;
  }
  if (t < 128) {
    cnt[t] = 0;
    const int n = n0 + t;
    er_l[t] = (n < NN) ? er[n] : 0.f;
  }
  __syncthreads();
  const int csr0 = s_csr0;

  // pass A: per-node histogram over the bin's 8 sub-slabs
#pragma unroll
  for (int rep = 0; rep < NREP2; ++rep) {
    const int c = bincur[rep * NBINS + b];
    const unsigned* sl = slab + (size_t)(b * NREP2 + rep) * SUBCAP;
    for (int i = t; i < c; i += 256)
      atomicAdd(&cnt[sl[i] >> 17], 1);
  }
  __syncthreads();

  // scan 128 counts (threads 0..127 active; barriers uniform)
  const int cme = (t < 128) ? cnt[t] : 0;
  sp[t] = cme;
  __syncthreads();
  for (int o = 1; o < 128; o <<= 1) {
    const int u = (t >= o && t < 128) ? sp[t - o] : 0;
    __syncthreads();
    if (t < 128) sp[t] += u;
    __syncthreads();
  }
  if (t < 128) {
    const int cur = csr0 + sp[t] - cme;
    cnt[t] = cur;
    if (n0 + t < NN) off[n0 + t] = cur;
  }
  if (b == NBINS - 1 && t == 0) off[NN] = NE;
  __syncthreads();

  // pass B: compute e and scatter into compact csr
#pragma unroll
  for (int rep = 0; rep < NREP2; ++rep) {
    const int c = bincur[rep * NBINS + b];
    const unsigned* sl = slab + (size_t)(b * NREP2 + rep) * SUBCAP;
    for (int i = t; i < c; i += 256) {
      const unsigned w = sl[i];
      const int dl = (int)(w >> 17);
      const int s = (int)(w & 0x1FFFFu);
      float e = el[s] + er_l[dl];
      e = e > 0.f ? e : 0.2f * e;
      const int pos = atomicAdd(&cnt[dl], 1);
      csr[pos] = (uint2){(unsigned)s, __float_as_uint(e)};
    }
  }
}

// ---------------- Kernel 5: per-node fused softmax + weighted gather-sum
__global__ __launch_bounds__(256) void node_aggregate(
    const ushort* __restrict__ xvb, const int* __restrict__ off,
    const uint2* __restrict__ csr, float* __restrict__ out) {
  const int wave = threadIdx.x >> 6, lane = threadIdx.x & 63;
  const int node = blockIdx.x * 4 + wave;
  if (node >= NN) return;
  const int base = off[node];
  const int deg = off[node + 1] - base;

  if (deg <= 64) {
    const bool valid = lane < deg;
    uint2 w = valid ? csr[base + lane] : (uint2){0u, 0u};
    int s = (int)w.x;
    float p = valid ? __expf(__uint_as_float(w.y)) : 0.f;
    float t = p;
#pragma unroll
    for (int o = 32; o; o >>= 1) t += __shfl_xor(t, o);
    p *= (deg > 0) ? (1.0f / t) : 0.f;

    const int fgrp = lane & 7, egrp = lane >> 3;
    float4 aLo = {0.f, 0.f, 0.f, 0.f};
    float4 aHi = {0.f, 0.f, 0.f, 0.f};
    const int nr = (deg + 7) >> 3;
#pragma unroll 4
    for (int r = 0; r < nr; ++r) {
      const int k = (r << 3) + egrp;
      const int sk = __shfl(s, k);
      const float pk = __shfl(p, k);
      if (k < deg) {
        const uint4 v = *(const uint4*)(xvb + (size_t)sk * OUT_F + (fgrp << 3));
        aLo.x += pk * __uint_as_float(v.x << 16);
        aLo.y += pk * __uint_as_float(v.x & 0xffff0000u);
        aLo.z += pk * __uint_as_float(v.y << 16);
        aLo.w += pk * __uint_as_float(v.y & 0xffff0000u);
        aHi.x += pk * __uint_as_float(v.z << 16);
        aHi.y += pk * __uint_as_float(v.z & 0xffff0000u);
        aHi.z += pk * __uint_as_float(v.w << 16);
        aHi.w += pk * __uint_as_float(v.w & 0xffff0000u);
      }
    }
#pragma unroll
    for (int o = 8; o <= 32; o <<= 1) {
      aLo.x += __shfl_xor(aLo.x, o);
      aLo.y += __shfl_xor(aLo.y, o);
      aLo.z += __shfl_xor(aLo.z, o);
      aLo.w += __shfl_xor(aLo.w, o);
      aHi.x += __shfl_xor(aHi.x, o);
      aHi.y += __shfl_xor(aHi.y, o);
      aHi.z += __shfl_xor(aHi.z, o);
      aHi.w += __shfl_xor(aHi.w, o);
    }
    if (egrp == 0) {
      float* op = out + (size_t)node * OUT_F + (fgrp << 3);
      *(float4*)op = aLo;
      *(float4*)(op + 4) = aHi;
    }
  } else {
    // fallback (deg>64, rare): stable 3-pass, lane = feature
    float m = -3.0e38f;
    for (int k = lane; k < deg; k += 64) m = fmaxf(m, __uint_as_float(csr[base + k].y));
#pragma unroll
    for (int o = 32; o; o >>= 1) m = fmaxf(m, __shfl_xor(m, o));
    float ssum = 0.f;
    for (int k = lane; k < deg; k += 64) ssum += __expf(__uint_as_float(csr[base + k].y) - m);
#pragma unroll
    for (int o = 32; o; o >>= 1) ssum += __shfl_xor(ssum, o);
    const float inv = 1.0f / ssum;
    float acc = 0.f;
    for (int k = 0; k < deg; ++k) {
      const uint2 w = csr[base + k];
      const float pk = __expf(__uint_as_float(w.y) - m) * inv;
      acc += pk * bf2f(xvb[(size_t)w.x * OUT_F + lane]);
    }
    out[(size_t)node * OUT_F + lane] = acc;
  }
}

extern "C" void kernel_launch(void* const* d_in, const int* in_sizes, int n_in,
                              void* d_out, int out_size, void* d_ws, size_t ws_size,
                              hipStream_t stream) {
  const float* x  = (const float*)d_in[0];
  const float* Wv = (const float*)d_in[1];
  const float* bv = (const float*)d_in[2];
  const float* wq = (const float*)d_in[3];
  const float* bq = (const float*)d_in[4];
  const float* wk = (const float*)d_in[5];
  const float* bk = (const float*)d_in[6];
  const int* src  = (const int*)d_in[7];
  const int* dst  = (const int*)d_in[8];
  float* out = (float*)d_out;

  // workspace layout (4-byte words), ~35 MB total:
  // xvb[NN*64 ushort] el[NN] er[NN] off[NN+1] csr[NE uint2]
  // slab[NBINS*NREP2*SUBCAP uint] wvt[8192 short] bincur[NREP2*NBINS]
  ushort* xvb = (ushort*)d_ws;
  float* el = (float*)(xvb + (size_t)NN * OUT_F);
  float* er = el + NN;
  int* off = (int*)(er + NN);
  uint2* csr = (uint2*)(off + NN + 2);
  unsigned* slab = (unsigned*)(csr + NE);
  short* wvt = (short*)(slab + (size_t)NBINS * NREP2 * SUBCAP);
  int* bincur = (int*)(wvt + IN_F * OUT_F);

  prep_w<<<(IN_F * OUT_F + 255) / 256, 256, 0, stream>>>(Wv, wvt, bincur);
  fused_tp<<<GEMM_WGS + P1_WGS, 256, 0, stream>>>(x, wvt, bv, wq, bq, wk, bk,
                                                  xvb, el, er, src, dst, bincur, slab);
  bin_scatter<<<NBINS, 256, 0, stream>>>(slab, bincur, el, er, off, csr);
  node_aggregate<<<(NN + 3) / 4, 256, 0, stream>>>(xvb, off, csr, out);
}

// Round 16
// 109.815 us; speedup vs baseline: 1.1373x; 1.0219x over previous
//
#include <hip/hip_runtime.h>
#include <hip/hip_bf16.h>

#define NN 100000
#define NE 1600000
#define IN_F 128
#define OUT_F 64
#define NBINS 782     // ceil(NN / 128)
#define BIN_SHIFT 7   // 128 nodes per bin
#define GEMM_WGS 1563 // ceil(NN / 64): 64 nodes per block
#define P1_WGS 391    // ceil(NE / 4096)
#define NREP2 8       // sub-slab replicas per bin
#define SUBCAP 384    // per (bin,rep); mean 256, sigma 16 -> 8-sigma slack
#define XS_STRIDE 132 // LDS row stride in floats (528B, 16B-aligned, conflict-light)

typedef __attribute__((ext_vector_type(8))) short bf16x8;
typedef __attribute__((ext_vector_type(4))) float f32x4;

__device__ __forceinline__ short f2bf(float f) {
  unsigned u = __float_as_uint(f);
  unsigned r = (u + 0x7fffu + ((u >> 16) & 1u)) >> 16;  // RNE
  return (short)r;
}
__device__ __forceinline__ float bf2f(ushort u) {
  return __uint_as_float(((unsigned)u) << 16);
}

// ---------------- Kernel 0: wvt[j][k] = bf16(Wv[k][j]); block 0 zeroes bincur
__global__ __launch_bounds__(256) void prep_w(
    const float* __restrict__ Wv, short* __restrict__ wvt,
    int* __restrict__ bincur) {
  if (blockIdx.x == 0)
    for (int i = threadIdx.x; i < NREP2 * NBINS; i += 256) bincur[i] = 0;
  const int i = blockIdx.x * 256 + threadIdx.x;
  if (i >= IN_F * OUT_F) return;
  const int j = i >> 7, k = i & 127;
  wvt[i] = f2bf(Wv[k * OUT_F + j]);
}

// ---------------- Fused dispatch. Blocks [0,P1_WGS) = edge binning (first, so
// both kinds progress from t0). Blocks [P1_WGS, +GEMM_WGS) = LDS-staged GEMM:
// 64 nodes/block staged to LDS once; wave nt computes 16-feature quadrant.
__global__ __launch_bounds__(256) void fused_tp(
    const float* __restrict__ x, const short* __restrict__ wvt,
    const float* __restrict__ bv, const float* __restrict__ wq,
    const float* __restrict__ bq, const float* __restrict__ wk,
    const float* __restrict__ bk,
    ushort* __restrict__ xvb, float* __restrict__ el, float* __restrict__ er,
    const int* __restrict__ src, const int* __restrict__ dst,
    int* __restrict__ bincur, unsigned* __restrict__ slab) {
  __shared__ __align__(16) char smem_[36352];
  if (blockIdx.x < P1_WGS) {
    // ----- binning body -----
    int* hist = (int*)smem_;
    int* base_ = hist + NBINS;
    const int pb = blockIdx.x;
    const int t = threadIdx.x;
    const int rep = pb & (NREP2 - 1);
    for (int i = t; i < NBINS; i += 256) hist[i] = 0;
    __syncthreads();
    const int e0 = pb * 4096;
    int sv[16], dv[16];
#pragma unroll
    for (int r = 0; r < 16; ++r) {
      const int i = e0 + r * 256 + t;
      if (i < NE) {
        sv[r] = src[i];
        dv[r] = dst[i];
        atomicAdd(&hist[dv[r] >> BIN_SHIFT], 1);
      } else {
        sv[r] = -1;
        dv[r] = 0;
      }
    }
    __syncthreads();
    for (int b = t; b < NBINS; b += 256) {
      base_[b] = (hist[b] > 0) ? atomicAdd(&bincur[rep * NBINS + b], hist[b]) : 0;
      hist[b] = 0;  // reuse as local cursor
    }
    __syncthreads();
#pragma unroll
    for (int r = 0; r < 16; ++r) {
      if (sv[r] >= 0) {
        const int s = sv[r], d = dv[r];
        const int b = d >> BIN_SHIFT;
        const unsigned dl = (unsigned)(d & 127);
        const int pos = base_[b] + atomicAdd(&hist[b], 1);
        slab[(size_t)(b * NREP2 + rep) * SUBCAP + pos] = (dl << 17) | (unsigned)s;
      }
    }
    return;
  }

  // ----- LDS-staged GEMM body -----
  float* xs = (float*)smem_;                 // [64][XS_STRIDE]
  float* pql = (float*)(smem_ + 64 * XS_STRIDE * 4);  // [64][4]
  float* pkl = pql + 256;                    // [64][4]
  const int gb = blockIdx.x - P1_WGS;
  const int node0 = gb * 64;
  const int t = threadIdx.x;
  const int wave = t >> 6, lane = t & 63;
  const int j15 = lane & 15, g = lane >> 4;

  // stage x[node0..node0+63][0..127] -> LDS (coalesced float4; clamp tail rows)
#pragma unroll
  for (int i = 0; i < 8; ++i) {
    const int idx = i * 256 + t;
    const int row = idx >> 5, col4 = (idx & 31) << 2;
    int grow = node0 + row;
    if (grow >= NN) grow = NN - 1;
    const float4 v = *(const float4*)(x + (size_t)grow * IN_F + col4);
    *(float4*)(xs + row * XS_STRIDE + col4) = v;
  }

  // B fragments for this wave's quadrant nt = wave (4 x 16B, L2-hot)
  const int nt = wave;
  bf16x8 b[4];
#pragma unroll
  for (int kt = 0; kt < 4; ++kt)
    b[kt] = *(const bf16x8*)(wvt + (size_t)(nt * 16 + j15) * IN_F + kt * 32 + g * 8);

  const float bvl = bv[nt * 16 + j15];
  const float wql = wq[nt * 16 + j15];
  const float wkl = wk[nt * 16 + j15];
  const float bq0 = bq[0], bk0 = bk[0];

  __syncthreads();

#pragma unroll
  for (int ntile = 0; ntile < 4; ++ntile) {
    f32x4 acc = (f32x4){0.f, 0.f, 0.f, 0.f};
#pragma unroll
    for (int kt = 0; kt < 4; ++kt) {
      const float* ap = xs + (ntile * 16 + j15) * XS_STRIDE + kt * 32 + g * 8;
      const float4 f0 = *(const float4*)ap;
      const float4 f1 = *(const float4*)(ap + 4);
      bf16x8 a;
      a[0] = f2bf(f0.x); a[1] = f2bf(f0.y); a[2] = f2bf(f0.z); a[3] = f2bf(f0.w);
      a[4] = f2bf(f1.x); a[5] = f2bf(f1.y); a[6] = f2bf(f1.z); a[7] = f2bf(f1.w);
      acc = __builtin_amdgcn_mfma_f32_16x16x32_bf16(a, b[kt], acc, 0, 0, 0);
    }
    // epilogue for this 16-node tile
#pragma unroll
    for (int r = 0; r < 4; ++r) {
      const int nl = ntile * 16 + g * 4 + r;
      const int node = node0 + nl;
      const float v = acc[r] + bvl;
      if (node < NN) xvb[(size_t)node * OUT_F + nt * 16 + j15] = (ushort)f2bf(v);
      float pq = v * wql, pk = v * wkl;
#pragma unroll
      for (int o = 1; o < 16; o <<= 1) {
        pq += __shfl_xor(pq, o);
        pk += __shfl_xor(pk, o);
      }
      if (j15 == 0) {
        pql[nl * 4 + nt] = pq;
        pkl[nl * 4 + nt] = pk;
      }
    }
  }
  __syncthreads();
  if (t < 64) {
    const int node = node0 + t;
    if (node < NN) {
      el[node] = pql[t * 4] + pql[t * 4 + 1] + pql[t * 4 + 2] + pql[t * 4 + 3] + bq0;
      er[node] = pkl[t * 4] + pkl[t * 4 + 1] + pkl[t * 4 + 2] + pkl[t * 4 + 3] + bk0;
    }
  }
}

// ---------------- Phase 2: one wg per 128-node bin. Redundant bin-level scan
// (L2-hot bincur), LDS per-node hist+scan -> off[], compute e, write csr.
__global__ __launch_bounds__(256) void bin_scatter(
    const unsigned* __restrict__ slab, const int* __restrict__ bincur,
    const float* __restrict__ el, const float* __restrict__ er,
    int* __restrict__ off, uint2* __restrict__ csr) {
  __shared__ int sp[256];
  __shared__ int cnt[128];     // counts, then cursors
  __shared__ float er_l[128];
  __shared__ int s_csr0;
  const int b = blockIdx.x, t = threadIdx.x;
  const int n0 = b << BIN_SHIFT;

  // redundant bin-level exclusive scan: thread t covers bins 4t..4t+3
  int v = 0;
#pragma unroll
  for (int j = 0; j < 4; ++j) {
    const int bb = 4 * t + j;
    if (bb < NBINS) {
#pragma unroll
      for (int r = 0; r < NREP2; ++r) v += bincur[r * NBINS + bb];
    }
  }
  sp[t] = v;
  __syncthreads();
  for (int o = 1; o < 256; o <<= 1) {
    const int u = (t >= o) ? sp[t - o] : 0;
    __syncthreads();
    sp[t] += u;
    __syncthreads();
  }
  if (t == 0) {
    const int q = b >> 2, rr = b & 3;
    int c = (q > 0) ? sp[q - 1] : 0;
    for (int j = 0; j < rr; ++j)
      for (int r = 0; r < NREP2; ++r) c += bincur[r * NBINS + (4 * q + j)];
    s_csr0 = c;
  }
  if (t < 128) {
    cnt[t] = 0;
    const int n = n0 + t;
    er_l[t] = (n < NN) ? er[n] : 0.f;
  }
  __syncthreads();
  const int csr0 = s_csr0;

  // pass A: per-node histogram over the bin's 8 sub-slabs
#pragma unroll
  for (int rep = 0; rep < NREP2; ++rep) {
    const int c = bincur[rep * NBINS + b];
    const unsigned* sl = slab + (size_t)(b * NREP2 + rep) * SUBCAP;
    for (int i = t; i < c; i += 256)
      atomicAdd(&cnt[sl[i] >> 17], 1);
  }
  __syncthreads();

  // scan 128 counts (threads 0..127 active; barriers uniform)
  const int cme = (t < 128) ? cnt[t] : 0;
  sp[t] = cme;
  __syncthreads();
  for (int o = 1; o < 128; o <<= 1) {
    const int u = (t >= o && t < 128) ? sp[t - o] : 0;
    __syncthreads();
    if (t < 128) sp[t] += u;
    __syncthreads();
  }
  if (t < 128) {
    const int cur = csr0 + sp[t] - cme;
    cnt[t] = cur;
    if (n0 + t < NN) off[n0 + t] = cur;
  }
  if (b == NBINS - 1 && t == 0) off[NN] = NE;
  __syncthreads();

  // pass B: compute e and scatter into compact csr
#pragma unroll
  for (int rep = 0; rep < NREP2; ++rep) {
    const int c = bincur[rep * NBINS + b];
    const unsigned* sl = slab + (size_t)(b * NREP2 + rep) * SUBCAP;
    for (int i = t; i < c; i += 256) {
      const unsigned w = sl[i];
      const int dl = (int)(w >> 17);
      const int s = (int)(w & 0x1FFFFu);
      float e = el[s] + er_l[dl];
      e = e > 0.f ? e : 0.2f * e;
      const int pos = atomicAdd(&cnt[dl], 1);
      csr[pos] = (uint2){(unsigned)s, __float_as_uint(e)};
    }
  }
}

// ---------------- Kernel 5: per-node fused softmax + weighted gather-sum
__global__ __launch_bounds__(256) void node_aggregate(
    const ushort* __restrict__ xvb, const int* __restrict__ off,
    const uint2* __restrict__ csr, float* __restrict__ out) {
  const int wave = threadIdx.x >> 6, lane = threadIdx.x & 63;
  const int node = blockIdx.x * 4 + wave;
  if (node >= NN) return;
  const int base = off[node];
  const int deg = off[node + 1] - base;

  if (deg <= 64) {
    const bool valid = lane < deg;
    uint2 w = valid ? csr[base + lane] : (uint2){0u, 0u};
    int s = (int)w.x;
    float p = valid ? __expf(__uint_as_float(w.y)) : 0.f;
    float t = p;
#pragma unroll
    for (int o = 32; o; o >>= 1) t += __shfl_xor(t, o);
    p *= (deg > 0) ? (1.0f / t) : 0.f;

    const int fgrp = lane & 7, egrp = lane >> 3;
    float4 aLo = {0.f, 0.f, 0.f, 0.f};
    float4 aHi = {0.f, 0.f, 0.f, 0.f};
    const int nr = (deg + 7) >> 3;
#pragma unroll 4
    for (int r = 0; r < nr; ++r) {
      const int k = (r << 3) + egrp;
      const int sk = __shfl(s, k);
      const float pk = __shfl(p, k);
      if (k < deg) {
        const uint4 v = *(const uint4*)(xvb + (size_t)sk * OUT_F + (fgrp << 3));
        aLo.x += pk * __uint_as_float(v.x << 16);
        aLo.y += pk * __uint_as_float(v.x & 0xffff0000u);
        aLo.z += pk * __uint_as_float(v.y << 16);
        aLo.w += pk * __uint_as_float(v.y & 0xffff0000u);
        aHi.x += pk * __uint_as_float(v.z << 16);
        aHi.y += pk * __uint_as_float(v.z & 0xffff0000u);
        aHi.z += pk * __uint_as_float(v.w << 16);
        aHi.w += pk * __uint_as_float(v.w & 0xffff0000u);
      }
    }
#pragma unroll
    for (int o = 8; o <= 32; o <<= 1) {
      aLo.x += __shfl_xor(aLo.x, o);
      aLo.y += __shfl_xor(aLo.y, o);
      aLo.z += __shfl_xor(aLo.z, o);
      aLo.w += __shfl_xor(aLo.w, o);
      aHi.x += __shfl_xor(aHi.x, o);
      aHi.y += __shfl_xor(aHi.y, o);
      aHi.z += __shfl_xor(aHi.z, o);
      aHi.w += __shfl_xor(aHi.w, o);
    }
    if (egrp == 0) {
      float* op = out + (size_t)node * OUT_F + (fgrp << 3);
      *(float4*)op = aLo;
      *(float4*)(op + 4) = aHi;
    }
  } else {
    // fallback (deg>64, rare): stable 3-pass, lane = feature
    float m = -3.0e38f;
    for (int k = lane; k < deg; k += 64) m = fmaxf(m, __uint_as_float(csr[base + k].y));
#pragma unroll
    for (int o = 32; o; o >>= 1) m = fmaxf(m, __shfl_xor(m, o));
    float ssum = 0.f;
    for (int k = lane; k < deg; k += 64) ssum += __expf(__uint_as_float(csr[base + k].y) - m);
#pragma unroll
    for (int o = 32; o; o >>= 1) ssum += __shfl_xor(ssum, o);
    const float inv = 1.0f / ssum;
    float acc = 0.f;
    for (int k = 0; k < deg; ++k) {
      const uint2 w = csr[base + k];
      const float pk = __expf(__uint_as_float(w.y) - m) * inv;
      acc += pk * bf2f(xvb[(size_t)w.x * OUT_F + lane]);
    }
    out[(size_t)node * OUT_F + lane] = acc;
  }
}

extern "C" void kernel_launch(void* const* d_in, const int* in_sizes, int n_in,
                              void* d_out, int out_size, void* d_ws, size_t ws_size,
                              hipStream_t stream) {
  const float* x  = (const float*)d_in[0];
  const float* Wv = (const float*)d_in[1];
  const float* bv = (const float*)d_in[2];
  const float* wq = (const float*)d_in[3];
  const float* bq = (const float*)d_in[4];
  const float* wk = (const float*)d_in[5];
  const float* bk = (const float*)d_in[6];
  const int* src  = (const int*)d_in[7];
  const int* dst  = (const int*)d_in[8];
  float* out = (float*)d_out;

  // workspace layout (4-byte words), ~35 MB total:
  // xvb[NN*64 ushort] el[NN] er[NN] off[NN+1] csr[NE uint2]
  // slab[NBINS*NREP2*SUBCAP uint] wvt[8192 short] bincur[NREP2*NBINS]
  ushort* xvb = (ushort*)d_ws;
  float* el = (float*)(xvb + (size_t)NN * OUT_F);
  float* er = el + NN;
  int* off = (int*)(er + NN);
  uint2* csr = (uint2*)(off + NN + 2);
  unsigned* slab = (unsigned*)(csr + NE);
  short* wvt = (short*)(slab + (size_t)NBINS * NREP2 * SUBCAP);
  int* bincur = (int*)(wvt + IN_F * OUT_F);

  prep_w<<<(IN_F * OUT_F + 255) / 256, 256, 0, stream>>>(Wv, wvt, bincur);
  fused_tp<<<P1_WGS + GEMM_WGS, 256, 0, stream>>>(x, wvt, bv, wq, bq, wk, bk,
                                                  xvb, el, er, src, dst, bincur, slab);
  bin_scatter<<<NBINS, 256, 0, stream>>>(slab, bincur, el, er, off, csr);
  node_aggregate<<<(NN + 3) / 4, 256, 0, stream>>>(xvb, off, csr, out);
}

// Round 17
// 108.517 us; speedup vs baseline: 1.1509x; 1.0120x over previous
//
#include <hip/hip_runtime.h>
#include <hip/hip_bf16.h>

#define NN 100000
#define NE 1600000
#define IN_F 128
#define OUT_F 64
#define NBINS 782     // ceil(NN / 128)
#define BIN_SHIFT 7   // 128 nodes per bin
#define GEMM_WGS 1563 // ceil(NN / 64): 64 nodes per block
#define P1_WGS 391    // ceil(NE / 4096)
#define NREP2 8       // sub-slab replicas per bin
#define SUBCAP 384    // per (bin,rep); mean 256, sigma 16 -> 8-sigma slack
#define XS_STRIDE 136 // LDS row stride in bf16 units (272B: 16B-aligned, 2-way bank alias = free)

typedef __attribute__((ext_vector_type(8))) short bf16x8;
typedef __attribute__((ext_vector_type(4))) float f32x4;

__device__ __forceinline__ short f2bf(float f) {
  unsigned u = __float_as_uint(f);
  unsigned r = (u + 0x7fffu + ((u >> 16) & 1u)) >> 16;  // RNE
  return (short)r;
}
__device__ __forceinline__ float bf2f(ushort u) {
  return __uint_as_float(((unsigned)u) << 16);
}

// ---------------- Kernel 0: wvt[j][k] = bf16(Wv[k][j]); block 0 zeroes bincur
__global__ __launch_bounds__(256) void prep_w(
    const float* __restrict__ Wv, short* __restrict__ wvt,
    int* __restrict__ bincur) {
  if (blockIdx.x == 0)
    for (int i = threadIdx.x; i < NREP2 * NBINS; i += 256) bincur[i] = 0;
  const int i = blockIdx.x * 256 + threadIdx.x;
  if (i >= IN_F * OUT_F) return;
  const int j = i >> 7, k = i & 127;
  wvt[i] = f2bf(Wv[k * OUT_F + j]);
}

// ---------------- Fused dispatch. Blocks [0,P1_WGS) = edge binning.
// Blocks [P1_WGS, +GEMM_WGS) = LDS-staged GEMM: x staged as BF16 (converted
// once at stage time); inner loop is pure ds_read_b128 + MFMA.
__global__ __launch_bounds__(256) void fused_tp(
    const float* __restrict__ x, const short* __restrict__ wvt,
    const float* __restrict__ bv, const float* __restrict__ wq,
    const float* __restrict__ bq, const float* __restrict__ wk,
    const float* __restrict__ bk,
    ushort* __restrict__ xvb, float* __restrict__ el, float* __restrict__ er,
    const int* __restrict__ src, const int* __restrict__ dst,
    int* __restrict__ bincur, unsigned* __restrict__ slab) {
  __shared__ __align__(16) char smem_[19712];
  if (blockIdx.x < P1_WGS) {
    // ----- binning body -----
    int* hist = (int*)smem_;
    int* base_ = hist + NBINS;
    const int pb = blockIdx.x;
    const int t = threadIdx.x;
    const int rep = pb & (NREP2 - 1);
    for (int i = t; i < NBINS; i += 256) hist[i] = 0;
    __syncthreads();
    const int e0 = pb * 4096;
    int sv[16], dv[16];
#pragma unroll
    for (int r = 0; r < 16; ++r) {
      const int i = e0 + r * 256 + t;
      if (i < NE) {
        sv[r] = src[i];
        dv[r] = dst[i];
        atomicAdd(&hist[dv[r] >> BIN_SHIFT], 1);
      } else {
        sv[r] = -1;
        dv[r] = 0;
      }
    }
    __syncthreads();
    for (int b = t; b < NBINS; b += 256) {
      base_[b] = (hist[b] > 0) ? atomicAdd(&bincur[rep * NBINS + b], hist[b]) : 0;
      hist[b] = 0;  // reuse as local cursor
    }
    __syncthreads();
#pragma unroll
    for (int r = 0; r < 16; ++r) {
      if (sv[r] >= 0) {
        const int s = sv[r], d = dv[r];
        const int b = d >> BIN_SHIFT;
        const unsigned dl = (unsigned)(d & 127);
        const int pos = base_[b] + atomicAdd(&hist[b], 1);
        slab[(size_t)(b * NREP2 + rep) * SUBCAP + pos] = (dl << 17) | (unsigned)s;
      }
    }
    return;
  }

  // ----- LDS-staged GEMM body (bf16 tile) -----
  ushort* xs = (ushort*)smem_;                          // [64][XS_STRIDE] bf16
  float* pql = (float*)(smem_ + 64 * XS_STRIDE * 2);    // [64][4]
  float* pkl = pql + 256;                               // [64][4]
  const int gb = blockIdx.x - P1_WGS;
  const int node0 = gb * 64;
  const int t = threadIdx.x;
  const int wave = t >> 6, lane = t & 63;
  const int j15 = lane & 15, g = lane >> 4;

  // stage x[node0..+63][0..127] -> LDS as bf16 (convert once, coalesced float4 in)
#pragma unroll
  for (int i = 0; i < 8; ++i) {
    const int idx = i * 256 + t;
    const int row = idx >> 5, col4 = (idx & 31) << 2;
    int grow = node0 + row;
    if (grow >= NN) grow = NN - 1;
    const float4 v = *(const float4*)(x + (size_t)grow * IN_F + col4);
    ushort4 h;
    h.x = (ushort)f2bf(v.x); h.y = (ushort)f2bf(v.y);
    h.z = (ushort)f2bf(v.z); h.w = (ushort)f2bf(v.w);
    *(ushort4*)(xs + row * XS_STRIDE + col4) = h;
  }

  // B fragments for this wave's quadrant nt = wave (4 x 16B, L2-hot)
  const int nt = wave;
  bf16x8 b[4];
#pragma unroll
  for (int kt = 0; kt < 4; ++kt)
    b[kt] = *(const bf16x8*)(wvt + (size_t)(nt * 16 + j15) * IN_F + kt * 32 + g * 8);

  const float bvl = bv[nt * 16 + j15];
  const float wql = wq[nt * 16 + j15];
  const float wkl = wk[nt * 16 + j15];
  const float bq0 = bq[0], bk0 = bk[0];

  __syncthreads();

#pragma unroll
  for (int ntile = 0; ntile < 4; ++ntile) {
    f32x4 acc = (f32x4){0.f, 0.f, 0.f, 0.f};
#pragma unroll
    for (int kt = 0; kt < 4; ++kt) {
      const bf16x8 a = *(const bf16x8*)(xs + (ntile * 16 + j15) * XS_STRIDE + kt * 32 + g * 8);
      acc = __builtin_amdgcn_mfma_f32_16x16x32_bf16(a, b[kt], acc, 0, 0, 0);
    }
    // epilogue for this 16-node tile
#pragma unroll
    for (int r = 0; r < 4; ++r) {
      const int nl = ntile * 16 + g * 4 + r;
      const int node = node0 + nl;
      const float v = acc[r] + bvl;
      if (node < NN) xvb[(size_t)node * OUT_F + nt * 16 + j15] = (ushort)f2bf(v);
      float pq = v * wql, pk = v * wkl;
#pragma unroll
      for (int o = 1; o < 16; o <<= 1) {
        pq += __shfl_xor(pq, o);
        pk += __shfl_xor(pk, o);
      }
      if (j15 == 0) {
        pql[nl * 4 + nt] = pq;
        pkl[nl * 4 + nt] = pk;
      }
    }
  }
  __syncthreads();
  if (t < 64) {
    const int node = node0 + t;
    if (node < NN) {
      el[node] = pql[t * 4] + pql[t * 4 + 1] + pql[t * 4 + 2] + pql[t * 4 + 3] + bq0;
      er[node] = pkl[t * 4] + pkl[t * 4 + 1] + pkl[t * 4 + 2] + pkl[t * 4 + 3] + bk0;
    }
  }
}

// ---------------- Phase 2: one wg per 128-node bin. Redundant bin-level scan
// (L2-hot bincur), LDS per-node hist+scan -> off[], compute e, write csr.
__global__ __launch_bounds__(256) void bin_scatter(
    const unsigned* __restrict__ slab, const int* __restrict__ bincur,
    const float* __restrict__ el, const float* __restrict__ er,
    int* __restrict__ off, uint2* __restrict__ csr) {
  __shared__ int sp[256];
  __shared__ int cnt[128];     // counts, then cursors
  __shared__ float er_l[128];
  __shared__ int s_csr0;
  const int b = blockIdx.x, t = threadIdx.x;
  const int n0 = b << BIN_SHIFT;

  // redundant bin-level exclusive scan: thread t covers bins 4t..4t+3
  int v = 0;
#pragma unroll
  for (int j = 0; j < 4; ++j) {
    const int bb = 4 * t + j;
    if (bb < NBINS) {
#pragma unroll
      for (int r = 0; r < NREP2; ++r) v += bincur[r * NBINS + bb];
    }
  }
  sp[t] = v;
  __syncthreads();
  for (int o = 1; o < 256; o <<= 1) {
    const int u = (t >= o) ? sp[t - o] : 0;
    __syncthreads();
    sp[t] += u;
    __syncthreads();
  }
  if (t == 0) {
    const int q = b >> 2, rr = b & 3;
    int c = (q > 0) ? sp[q - 1] : 0;
    for (int j = 0; j < rr; ++j)
      for (int r = 0; r < NREP2; ++r) c += bincur[r * NBINS + (4 * q + j)];
    s_csr0 = c;
  }
  if (t < 128) {
    cnt[t] = 0;
    const int n = n0 + t;
    er_l[t] = (n < NN) ? er[n] : 0.f;
  }
  __syncthreads();
  const int csr0 = s_csr0;

  // pass A: per-node histogram over the bin's 8 sub-slabs
#pragma unroll
  for (int rep = 0; rep < NREP2; ++rep) {
    const int c = bincur[rep * NBINS + b];
    const unsigned* sl = slab + (size_t)(b * NREP2 + rep) * SUBCAP;
    for (int i = t; i < c; i += 256)
      atomicAdd(&cnt[sl[i] >> 17], 1);
  }
  __syncthreads();

  // scan 128 counts (threads 0..127 active; barriers uniform)
  const int cme = (t < 128) ? cnt[t] : 0;
  sp[t] = cme;
  __syncthreads();
  for (int o = 1; o < 128; o <<= 1) {
    const int u = (t >= o && t < 128) ? sp[t - o] : 0;
    __syncthreads();
    if (t < 128) sp[t] += u;
    __syncthreads();
  }
  if (t < 128) {
    const int cur = csr0 + sp[t] - cme;
    cnt[t] = cur;
    if (n0 + t < NN) off[n0 + t] = cur;
  }
  if (b == NBINS - 1 && t == 0) off[NN] = NE;
  __syncthreads();

  // pass B: compute e and scatter into compact csr
#pragma unroll
  for (int rep = 0; rep < NREP2; ++rep) {
    const int c = bincur[rep * NBINS + b];
    const unsigned* sl = slab + (size_t)(b * NREP2 + rep) * SUBCAP;
    for (int i = t; i < c; i += 256) {
      const unsigned w = sl[i];
      const int dl = (int)(w >> 17);
      const int s = (int)(w & 0x1FFFFu);
      float e = el[s] + er_l[dl];
      e = e > 0.f ? e : 0.2f * e;
      const int pos = atomicAdd(&cnt[dl], 1);
      csr[pos] = (uint2){(unsigned)s, __float_as_uint(e)};
    }
  }
}

// ---------------- Kernel 5: per-node fused softmax + weighted gather-sum
__global__ __launch_bounds__(256) void node_aggregate(
    const ushort* __restrict__ xvb, const int* __restrict__ off,
    const uint2* __restrict__ csr, float* __restrict__ out) {
  const int wave = threadIdx.x >> 6, lane = threadIdx.x & 63;
  const int node = blockIdx.x * 4 + wave;
  if (node >= NN) return;
  const int base = off[node];
  const int deg = off[node + 1] - base;

  if (deg <= 64) {
    const bool valid = lane < deg;
    uint2 w = valid ? csr[base + lane] : (uint2){0u, 0u};
    int s = (int)w.x;
    float p = valid ? __expf(__uint_as_float(w.y)) : 0.f;
    float t = p;
#pragma unroll
    for (int o = 32; o; o >>= 1) t += __shfl_xor(t, o);
    p *= (deg > 0) ? (1.0f / t) : 0.f;

    const int fgrp = lane & 7, egrp = lane >> 3;
    float4 aLo = {0.f, 0.f, 0.f, 0.f};
    float4 aHi = {0.f, 0.f, 0.f, 0.f};
    const int nr = (deg + 7) >> 3;
#pragma unroll 4
    for (int r = 0; r < nr; ++r) {
      const int k = (r << 3) + egrp;
      const int sk = __shfl(s, k);
      const float pk = __shfl(p, k);
      if (k < deg) {
        const uint4 v = *(const uint4*)(xvb + (size_t)sk * OUT_F + (fgrp << 3));
        aLo.x += pk * __uint_as_float(v.x << 16);
        aLo.y += pk * __uint_as_float(v.x & 0xffff0000u);
        aLo.z += pk * __uint_as_float(v.y << 16);
        aLo.w += pk * __uint_as_float(v.y & 0xffff0000u);
        aHi.x += pk * __uint_as_float(v.z << 16);
        aHi.y += pk * __uint_as_float(v.z & 0xffff0000u);
        aHi.z += pk * __uint_as_float(v.w << 16);
        aHi.w += pk * __uint_as_float(v.w & 0xffff0000u);
      }
    }
#pragma unroll
    for (int o = 8; o <= 32; o <<= 1) {
      aLo.x += __shfl_xor(aLo.x, o);
      aLo.y += __shfl_xor(aLo.y, o);
      aLo.z += __shfl_xor(aLo.z, o);
      aLo.w += __shfl_xor(aLo.w, o);
      aHi.x += __shfl_xor(aHi.x, o);
      aHi.y += __shfl_xor(aHi.y, o);
      aHi.z += __shfl_xor(aHi.z, o);
      aHi.w += __shfl_xor(aHi.w, o);
    }
    if (egrp == 0) {
      float* op = out + (size_t)node * OUT_F + (fgrp << 3);
      *(float4*)op = aLo;
      *(float4*)(op + 4) = aHi;
    }
  } else {
    // fallback (deg>64, rare): stable 3-pass, lane = feature
    float m = -3.0e38f;
    for (int k = lane; k < deg; k += 64) m = fmaxf(m, __uint_as_float(csr[base + k].y));
#pragma unroll
    for (int o = 32; o; o >>= 1) m = fmaxf(m, __shfl_xor(m, o));
    float ssum = 0.f;
    for (int k = lane; k < deg; k += 64) ssum += __expf(__uint_as_float(csr[base + k].y) - m);
#pragma unroll
    for (int o = 32; o; o >>= 1) ssum += __shfl_xor(ssum, o);
    const float inv = 1.0f / ssum;
    float acc = 0.f;
    for (int k = 0; k < deg; ++k) {
      const uint2 w = csr[base + k];
      const float pk = __expf(__uint_as_float(w.y) - m) * inv;
      acc += pk * bf2f(xvb[(size_t)w.x * OUT_F + lane]);
    }
    out[(size_t)node * OUT_F + lane] = acc;
  }
}

extern "C" void kernel_launch(void* const* d_in, const int* in_sizes, int n_in,
                              void* d_out, int out_size, void* d_ws, size_t ws_size,
                              hipStream_t stream) {
  const float* x  = (const float*)d_in[0];
  const float* Wv = (const float*)d_in[1];
  const float* bv = (const float*)d_in[2];
  const float* wq = (const float*)d_in[3];
  const float* bq = (const float*)d_in[4];
  const float* wk = (const float*)d_in[5];
  const float* bk = (const float*)d_in[6];
  const int* src  = (const int*)d_in[7];
  const int* dst  = (const int*)d_in[8];
  float* out = (float*)d_out;

  // workspace layout (4-byte words), ~35 MB total:
  // xvb[NN*64 ushort] el[NN] er[NN] off[NN+1] csr[NE uint2]
  // slab[NBINS*NREP2*SUBCAP uint] wvt[8192 short] bincur[NREP2*NBINS]
  ushort* xvb = (ushort*)d_ws;
  float* el = (float*)(xvb + (size_t)NN * OUT_F);
  float* er = el + NN;
  int* off = (int*)(er + NN);
  uint2* csr = (uint2*)(off + NN + 2);
  unsigned* slab = (unsigned*)(csr + NE);
  short* wvt = (short*)(slab + (size_t)NBINS * NREP2 * SUBCAP);
  int* bincur = (int*)(wvt + IN_F * OUT_F);

  prep_w<<<(IN_F * OUT_F + 255) / 256, 256, 0, stream>>>(Wv, wvt, bincur);
  fused_tp<<<P1_WGS + GEMM_WGS, 256, 0, stream>>>(x, wvt, bv, wq, bq, wk, bk,
                                                  xvb, el, er, src, dst, bincur, slab);
  bin_scatter<<<NBINS, 256, 0, stream>>>(slab, bincur, el, er, off, csr);
  node_aggregate<<<(NN + 3) / 4, 256, 0, stream>>>(xvb, off, csr, out);
}